// Round 1
// baseline (1035.628 us; speedup 1.0000x reference)
//
#include <hip/hip_runtime.h>
#include <hip/hip_bf16.h>

// Problem: STN  B=16, H=W=256, C=32, FILTER=64 (f4=16, f2=32)
// Pipeline: conv1(32->16)+relu+pool -> conv2(16->32)+relu+pool ->
//           conv3(32->32)+relu+pool -> mean -> d1(32->64) -> d2(64->32) ->
//           d3(32->6)=theta -> affine grid -> bilinear sample of x.
//
// Workspace layout (floats):
//   p1    : 16*127*127*16 = 4,129,024
//   p2    : 16* 62* 62*32 = 1,968,128
//   p3    : 16* 30* 30*32 =   460,800
//   theta : 16*6          =        96
// total ~26.2 MB

#define P1_ELEMS 4129024
#define P2_ELEMS 1968128
#define P3_ELEMS 460800

// ---------------------------------------------------------------- conv1+pool
// x:(16,256,256,32)  W1:(3,3,32,16)  b1:(16)  -> p1:(16,127,127,16)
__global__ __launch_bounds__(256) void conv1_pool_kernel(
    const float* __restrict__ x, const float* __restrict__ W1,
    const float* __restrict__ b1, float* __restrict__ p1)
{
    __shared__ float wlds[3*3*32*16];          // 18 KB
    for (int i = threadIdx.x; i < 3*3*32*16; i += 256) wlds[i] = W1[i];
    __syncthreads();

    const int b  = blockIdx.z;
    const int ph = blockIdx.y * 16 + (threadIdx.x >> 4);
    const int pw = blockIdx.x * 16 + (threadIdx.x & 15);
    const bool valid = (ph < 127) && (pw < 127);
    const int hp = valid ? ph : 126;
    const int wp = valid ? pw : 126;

    const float* xb = x + (size_t)b * (256*256*32);
    const int h0 = 2*hp, w0 = 2*wp;

    float acc[4][16];
    #pragma unroll
    for (int f = 0; f < 16; ++f) {
        float bv = b1[f];
        acc[0][f]=bv; acc[1][f]=bv; acc[2][f]=bv; acc[3][f]=bv;
    }

    for (int kh = 0; kh < 3; ++kh)
    for (int kw = 0; kw < 3; ++kw) {
        #pragma unroll
        for (int c4 = 0; c4 < 8; ++c4) {
            float xr[4][4];
            #pragma unroll
            for (int p = 0; p < 4; ++p) {
                const int hh = h0 + (p >> 1) + kh;
                const int ww = w0 + (p & 1) + kw;
                const float4 xv = *(const float4*)(xb + ((size_t)hh*256 + ww)*32 + c4*4);
                xr[p][0]=xv.x; xr[p][1]=xv.y; xr[p][2]=xv.z; xr[p][3]=xv.w;
            }
            const float* wp4 = &wlds[((kh*3 + kw)*32 + c4*4) * 16];
            #pragma unroll
            for (int cc = 0; cc < 4; ++cc) {
                float wv[16];
                #pragma unroll
                for (int q = 0; q < 4; ++q) {
                    const float4 w4 = *(const float4*)(wp4 + cc*16 + 4*q);
                    wv[4*q+0]=w4.x; wv[4*q+1]=w4.y; wv[4*q+2]=w4.z; wv[4*q+3]=w4.w;
                }
                #pragma unroll
                for (int p = 0; p < 4; ++p) {
                    const float xc = xr[p][cc];
                    #pragma unroll
                    for (int f = 0; f < 16; ++f) acc[p][f] += xc * wv[f];
                }
            }
        }
    }

    if (valid) {
        float out[16];
        #pragma unroll
        for (int f = 0; f < 16; ++f) {
            float m = fmaxf(fmaxf(acc[0][f], acc[1][f]), fmaxf(acc[2][f], acc[3][f]));
            out[f] = fmaxf(m, 0.0f);   // max(relu(.)) == relu(max(.))
        }
        float* dst = p1 + (((size_t)b*127 + ph)*127 + pw) * 16;
        #pragma unroll
        for (int q = 0; q < 4; ++q)
            *(float4*)(dst + 4*q) = make_float4(out[4*q], out[4*q+1], out[4*q+2], out[4*q+3]);
    }
}

// ---------------------------------------------------------------- conv2+pool
// p1:(16,127,127,16)  W2:(3,3,16,32)  b2:(32) -> p2:(16,62,62,32)
__global__ __launch_bounds__(256) void conv2_pool_kernel(
    const float* __restrict__ p1, const float* __restrict__ W2,
    const float* __restrict__ b2, float* __restrict__ p2)
{
    __shared__ float wlds[3*3*16*32];          // 18 KB
    for (int i = threadIdx.x; i < 3*3*16*32; i += 256) wlds[i] = W2[i];
    __syncthreads();

    const int b   = blockIdx.z;
    const int tid = threadIdx.x;
    const int fg  = tid >> 7;                  // 0/1 -> filters [fg*16, fg*16+16)
    const int rem = tid & 127;
    const int ph  = blockIdx.y * 8  + (rem >> 4);
    const int pw  = blockIdx.x * 16 + (rem & 15);
    const bool valid = (ph < 62) && (pw < 62);
    const int hp = valid ? ph : 61;
    const int wp = valid ? pw : 61;

    const float* xb = p1 + (size_t)b * (127*127*16);
    const int h0 = 2*hp, w0 = 2*wp;

    float acc[4][16];
    #pragma unroll
    for (int f = 0; f < 16; ++f) {
        float bv = b2[fg*16 + f];
        acc[0][f]=bv; acc[1][f]=bv; acc[2][f]=bv; acc[3][f]=bv;
    }

    for (int kh = 0; kh < 3; ++kh)
    for (int kw = 0; kw < 3; ++kw) {
        #pragma unroll
        for (int c4 = 0; c4 < 4; ++c4) {
            float xr[4][4];
            #pragma unroll
            for (int p = 0; p < 4; ++p) {
                const int hh = h0 + (p >> 1) + kh;
                const int ww = w0 + (p & 1) + kw;
                const float4 xv = *(const float4*)(xb + ((size_t)hh*127 + ww)*16 + c4*4);
                xr[p][0]=xv.x; xr[p][1]=xv.y; xr[p][2]=xv.z; xr[p][3]=xv.w;
            }
            #pragma unroll
            for (int cc = 0; cc < 4; ++cc) {
                const float* wb_ = &wlds[((kh*3 + kw)*16 + c4*4 + cc) * 32 + fg*16];
                float wv[16];
                #pragma unroll
                for (int q = 0; q < 4; ++q) {
                    const float4 w4 = *(const float4*)(wb_ + 4*q);
                    wv[4*q+0]=w4.x; wv[4*q+1]=w4.y; wv[4*q+2]=w4.z; wv[4*q+3]=w4.w;
                }
                #pragma unroll
                for (int p = 0; p < 4; ++p) {
                    const float xc = xr[p][cc];
                    #pragma unroll
                    for (int f = 0; f < 16; ++f) acc[p][f] += xc * wv[f];
                }
            }
        }
    }

    if (valid) {
        float out[16];
        #pragma unroll
        for (int f = 0; f < 16; ++f) {
            float m = fmaxf(fmaxf(acc[0][f], acc[1][f]), fmaxf(acc[2][f], acc[3][f]));
            out[f] = fmaxf(m, 0.0f);
        }
        float* dst = p2 + (((size_t)b*62 + ph)*62 + pw) * 32 + fg*16;
        #pragma unroll
        for (int q = 0; q < 4; ++q)
            *(float4*)(dst + 4*q) = make_float4(out[4*q], out[4*q+1], out[4*q+2], out[4*q+3]);
    }
}

// ---------------------------------------------------------------- conv3+pool
// p2:(16,62,62,32)  W3:(3,3,32,32)  b3:(32) -> p3:(16,30,30,32)
__global__ __launch_bounds__(256) void conv3_pool_kernel(
    const float* __restrict__ p2, const float* __restrict__ W3,
    const float* __restrict__ b3, float* __restrict__ p3)
{
    __shared__ float wlds[3*3*32*32];          // 36 KB
    for (int i = threadIdx.x; i < 3*3*32*32; i += 256) wlds[i] = W3[i];
    __syncthreads();

    const int b   = blockIdx.z;
    const int tid = threadIdx.x;
    const int fg  = tid >> 7;
    const int rem = tid & 127;
    const int ph  = blockIdx.y * 8  + (rem >> 4);
    const int pw  = blockIdx.x * 16 + (rem & 15);
    const bool valid = (ph < 30) && (pw < 30);
    const int hp = valid ? ph : 29;
    const int wp = valid ? pw : 29;

    const float* xb = p2 + (size_t)b * (62*62*32);
    const int h0 = 2*hp, w0 = 2*wp;

    float acc[4][16];
    #pragma unroll
    for (int f = 0; f < 16; ++f) {
        float bv = b3[fg*16 + f];
        acc[0][f]=bv; acc[1][f]=bv; acc[2][f]=bv; acc[3][f]=bv;
    }

    for (int kh = 0; kh < 3; ++kh)
    for (int kw = 0; kw < 3; ++kw) {
        #pragma unroll
        for (int c4 = 0; c4 < 8; ++c4) {
            float xr[4][4];
            #pragma unroll
            for (int p = 0; p < 4; ++p) {
                const int hh = h0 + (p >> 1) + kh;
                const int ww = w0 + (p & 1) + kw;
                const float4 xv = *(const float4*)(xb + ((size_t)hh*62 + ww)*32 + c4*4);
                xr[p][0]=xv.x; xr[p][1]=xv.y; xr[p][2]=xv.z; xr[p][3]=xv.w;
            }
            #pragma unroll
            for (int cc = 0; cc < 4; ++cc) {
                const float* wb_ = &wlds[((kh*3 + kw)*32 + c4*4 + cc) * 32 + fg*16];
                float wv[16];
                #pragma unroll
                for (int q = 0; q < 4; ++q) {
                    const float4 w4 = *(const float4*)(wb_ + 4*q);
                    wv[4*q+0]=w4.x; wv[4*q+1]=w4.y; wv[4*q+2]=w4.z; wv[4*q+3]=w4.w;
                }
                #pragma unroll
                for (int p = 0; p < 4; ++p) {
                    const float xc = xr[p][cc];
                    #pragma unroll
                    for (int f = 0; f < 16; ++f) acc[p][f] += xc * wv[f];
                }
            }
        }
    }

    if (valid) {
        float out[16];
        #pragma unroll
        for (int f = 0; f < 16; ++f) {
            float m = fmaxf(fmaxf(acc[0][f], acc[1][f]), fmaxf(acc[2][f], acc[3][f]));
            out[f] = fmaxf(m, 0.0f);
        }
        float* dst = p3 + (((size_t)b*30 + ph)*30 + pw) * 32 + fg*16;
        #pragma unroll
        for (int q = 0; q < 4; ++q)
            *(float4*)(dst + 4*q) = make_float4(out[4*q], out[4*q+1], out[4*q+2], out[4*q+3]);
    }
}

// ----------------------------------------------------------------- head
// p3:(16,30,30,32) -> mean(16,32) -> d1 relu (16,64) -> d2 relu (16,32)
// -> theta (16,6).  One block per batch element.
__global__ __launch_bounds__(256) void head_kernel(
    const float* __restrict__ p3,
    const float* __restrict__ D1, const float* __restrict__ db1,
    const float* __restrict__ D2, const float* __restrict__ db2,
    const float* __restrict__ D3, const float* __restrict__ db3,
    float* __restrict__ theta)
{
    __shared__ float red[8][32];
    __shared__ float hmean[32];
    __shared__ float h1[64];
    __shared__ float h2[32];

    const int b   = blockIdx.x;
    const int tid = threadIdx.x;
    const int c = tid & 31, r = tid >> 5;       // r in 0..7

    const float* p = p3 + (size_t)b * (900*32);
    float s = 0.0f;
    for (int i = r; i < 900; i += 8) s += p[i*32 + c];
    red[r][c] = s;
    __syncthreads();

    if (tid < 32) {
        float m = 0.0f;
        #pragma unroll
        for (int j = 0; j < 8; ++j) m += red[j][tid];
        hmean[tid] = m * (1.0f / 900.0f);
    }
    __syncthreads();

    if (tid < 64) {
        float a = db1[tid];
        #pragma unroll
        for (int k = 0; k < 32; ++k) a += hmean[k] * D1[k*64 + tid];
        h1[tid] = fmaxf(a, 0.0f);
    }
    __syncthreads();

    if (tid < 32) {
        float a = db2[tid];
        #pragma unroll
        for (int k = 0; k < 64; ++k) a += h1[k] * D2[k*32 + tid];
        h2[tid] = fmaxf(a, 0.0f);
    }
    __syncthreads();

    if (tid < 6) {
        float a = db3[tid];
        #pragma unroll
        for (int k = 0; k < 32; ++k) a += h2[k] * D3[k*6 + tid];
        theta[b*6 + tid] = a;
    }
}

// ----------------------------------------------------------------- sampler
// out[b,h,w,c] = bilinear(x[b], xp(b,h,w), yp(b,h,w)).
// thread = (b,h,w,c4); 8 lanes cover one pixel's 32 channels (coalesced).
__global__ __launch_bounds__(256) void sampler_kernel(
    const float* __restrict__ x, const float* __restrict__ theta,
    float* __restrict__ out)
{
    const int t  = blockIdx.x * 256 + threadIdx.x;
    const int c4 = t & 7;
    const int w  = (t >> 3) & 255;
    const int h  = (t >> 11) & 255;
    const int b  = t >> 19;

    const float* th = theta + b*6;
    const float gx = -1.0f + (float)w * (2.0f / 255.0f);
    const float gy = -1.0f + (float)h * (2.0f / 255.0f);
    const float xS = th[0]*gx + th[1]*gy + th[2];
    const float yS = th[3]*gx + th[4]*gy + th[5];
    const float xp = 0.5f * (xS + 1.0f) * 254.0f;
    const float yp = 0.5f * (yS + 1.0f) * 254.0f;

    int x0 = (int)floorf(xp), y0 = (int)floorf(yp);
    int x1 = x0 + 1,          y1 = y0 + 1;
    x0 = x0 < 0 ? 0 : (x0 > 255 ? 255 : x0);
    x1 = x1 < 0 ? 0 : (x1 > 255 ? 255 : x1);
    y0 = y0 < 0 ? 0 : (y0 > 255 ? 255 : y0);
    y1 = y1 < 0 ? 0 : (y1 > 255 ? 255 : y1);

    // weights from CLIPPED coords, exactly like the reference
    const float x0f = (float)x0, x1f = (float)x1;
    const float y0f = (float)y0, y1f = (float)y1;
    const float wa = (x1f - xp) * (y1f - yp);
    const float wb = (x1f - xp) * (yp - y0f);
    const float wc = (xp - x0f) * (y1f - yp);
    const float wd = (xp - x0f) * (yp - y0f);

    const float* xb = x + (size_t)b * (256*256*32) + c4*4;
    const float4 Ia = *(const float4*)(xb + ((size_t)y0*256 + x0)*32);
    const float4 Ib = *(const float4*)(xb + ((size_t)y1*256 + x0)*32);
    const float4 Ic = *(const float4*)(xb + ((size_t)y0*256 + x1)*32);
    const float4 Id = *(const float4*)(xb + ((size_t)y1*256 + x1)*32);

    float4 o;
    o.x = wa*Ia.x + wb*Ib.x + wc*Ic.x + wd*Id.x;
    o.y = wa*Ia.y + wb*Ib.y + wc*Ic.y + wd*Id.y;
    o.z = wa*Ia.z + wb*Ib.z + wc*Ic.z + wd*Id.z;
    o.w = wa*Ia.w + wb*Ib.w + wc*Ic.w + wd*Id.w;
    ((float4*)out)[t] = o;
}

// ----------------------------------------------------------------- launch
extern "C" void kernel_launch(void* const* d_in, const int* in_sizes, int n_in,
                              void* d_out, int out_size, void* d_ws, size_t ws_size,
                              hipStream_t stream) {
    const float* x   = (const float*)d_in[0];
    const float* W1  = (const float*)d_in[1];
    const float* b1  = (const float*)d_in[2];
    const float* W2  = (const float*)d_in[3];
    const float* b2  = (const float*)d_in[4];
    const float* W3  = (const float*)d_in[5];
    const float* b3  = (const float*)d_in[6];
    const float* D1  = (const float*)d_in[7];
    const float* db1 = (const float*)d_in[8];
    const float* D2  = (const float*)d_in[9];
    const float* db2 = (const float*)d_in[10];
    const float* D3  = (const float*)d_in[11];
    const float* db3 = (const float*)d_in[12];
    float* out = (float*)d_out;

    float* p1    = (float*)d_ws;
    float* p2    = p1 + P1_ELEMS;
    float* p3    = p2 + P2_ELEMS;
    float* theta = p3 + P3_ELEMS;

    conv1_pool_kernel<<<dim3(8, 8, 16),  256, 0, stream>>>(x,  W1, b1, p1);
    conv2_pool_kernel<<<dim3(4, 8, 16),  256, 0, stream>>>(p1, W2, b2, p2);
    conv3_pool_kernel<<<dim3(2, 4, 16),  256, 0, stream>>>(p2, W3, b3, p3);
    head_kernel      <<<dim3(16),        256, 0, stream>>>(p3, D1, db1, D2, db2, D3, db3, theta);
    sampler_kernel   <<<dim3(32768),     256, 0, stream>>>(x, theta, out);
}

// Round 2
// 522.864 us; speedup vs baseline: 1.9807x; 1.9807x over previous
//
#include <hip/hip_runtime.h>
#include <hip/hip_bf16.h>

// Problem: STN  B=16, H=W=256, C=32, FILTER=64 (f4=16, f2=32)
//
// Workspace layout (floats):
//   p1    : 16*127*127*16 = 4,129,024
//   p2    : 16* 62* 62*32 = 1,968,128
//   p3    : 16* 30* 30*32 =   460,800
//   theta : 16*6          =        96

#define P1_ELEMS 4129024
#define P2_ELEMS 1968128
#define P3_ELEMS 460800

// ---------------------------------------------------------------- conv1+pool
// x:(16,256,256,32)  W1:(3,3,32,16)  b1:(16)  -> p1:(16,127,127,16)
// Block: 256 threads -> pooled tile 4 rows x 16 cols x 16 filters.
// Input tile 10x34x32 fp32 staged in LDS (coalesced), weights in LDS.
// LDS = 43520 + 18432 = 60.5 KB -> 2 blocks/CU.
#define C1_ROWS 10
#define C1_COLS 34

__global__ __launch_bounds__(256) void conv1_pool_kernel(
    const float* __restrict__ x, const float* __restrict__ W1,
    const float* __restrict__ b1, float* __restrict__ p1)
{
    __shared__ float xt[C1_ROWS * C1_COLS * 32];   // 43520 B
    __shared__ float wlds[3*3*32*16];              // 18432 B

    const int tid = threadIdx.x;
    for (int i = tid; i < 3*3*32*16; i += 256) wlds[i] = W1[i];

    const int b   = blockIdx.z;
    const int ph0 = blockIdx.y * 4;
    const int pw0 = blockIdx.x * 16;
    const float* xb = x + (size_t)b * (256*256*32);

    // ---- stage input tile: rows 2*ph0..+9, cols 2*pw0..+33 (clamped).
    // channel-chunk slot swizzled by (pixel_col >> 1) so compute reads
    // (stride-2 pooled cols) spread over all 8 bank groups.
    for (int i = tid; i < C1_ROWS * C1_COLS * 8; i += 256) {
        const int dr  = i / (C1_COLS * 8);
        const int rem = i - dr * (C1_COLS * 8);
        const int j   = rem >> 3;
        const int ch  = rem & 7;
        int r_in = 2*ph0 + dr; if (r_in > 255) r_in = 255;
        int c_in = 2*pw0 + j;  if (c_in > 255) c_in = 255;
        const float4 v = *(const float4*)(xb + ((size_t)r_in*256 + c_in)*32 + ch*4);
        const int slot = (ch + (j >> 1)) & 7;
        *(float4*)(&xt[(dr * C1_COLS + j) * 32 + slot * 4]) = v;
    }
    __syncthreads();

    const int fq  = tid & 3;           // filters 4*fq .. 4*fq+3
    const int pix = tid >> 2;          // 0..63
    const int row = pix >> 4;          // 0..3 pooled row in tile
    const int col = pix & 15;          // 0..15 pooled col in tile
    const int lr  = 2 * row;
    const int lc  = 2 * col;

    float4 acc[4];
    {
        const float4 bv = *(const float4*)(b1 + 4*fq);
        acc[0] = bv; acc[1] = bv; acc[2] = bv; acc[3] = bv;
    }

    for (int kh = 0; kh < 3; ++kh)
    for (int kw = 0; kw < 3; ++kw) {
        #pragma unroll
        for (int c4 = 0; c4 < 8; ++c4) {
            float4 xv[4];
            #pragma unroll
            for (int p = 0; p < 4; ++p) {
                const int rr   = lr + (p >> 1) + kh;
                const int jj   = lc + (p & 1) + kw;
                const int slot = (c4 + (jj >> 1)) & 7;
                xv[p] = *(const float4*)(&xt[(rr * C1_COLS + jj) * 32 + slot * 4]);
            }
            const float* wp_ = &wlds[((kh*3 + kw)*32 + c4*4) * 16 + 4*fq];
            #pragma unroll
            for (int cc = 0; cc < 4; ++cc) {
                const float4 w4 = *(const float4*)(wp_ + cc*16);
                #pragma unroll
                for (int p = 0; p < 4; ++p) {
                    const float xc = (cc == 0) ? xv[p].x : (cc == 1) ? xv[p].y
                                   : (cc == 2) ? xv[p].z : xv[p].w;
                    acc[p].x += xc * w4.x;
                    acc[p].y += xc * w4.y;
                    acc[p].z += xc * w4.z;
                    acc[p].w += xc * w4.w;
                }
            }
        }
    }

    const int ph = ph0 + row, pw = pw0 + col;
    if (ph < 127 && pw < 127) {
        float4 o;
        o.x = fmaxf(fmaxf(fmaxf(acc[0].x, acc[1].x), fmaxf(acc[2].x, acc[3].x)), 0.0f);
        o.y = fmaxf(fmaxf(fmaxf(acc[0].y, acc[1].y), fmaxf(acc[2].y, acc[3].y)), 0.0f);
        o.z = fmaxf(fmaxf(fmaxf(acc[0].z, acc[1].z), fmaxf(acc[2].z, acc[3].z)), 0.0f);
        o.w = fmaxf(fmaxf(fmaxf(acc[0].w, acc[1].w), fmaxf(acc[2].w, acc[3].w)), 0.0f);
        *(float4*)(p1 + (((size_t)b*127 + ph)*127 + pw) * 16 + 4*fq) = o;
    }
}

// ---------------------------------------------------------------- conv2+pool
// p1:(16,127,127,16)  W2:(3,3,16,32)  b2:(32) -> p2:(16,62,62,32)
__global__ __launch_bounds__(256) void conv2_pool_kernel(
    const float* __restrict__ p1, const float* __restrict__ W2,
    const float* __restrict__ b2, float* __restrict__ p2)
{
    __shared__ float wlds[3*3*16*32];          // 18 KB
    for (int i = threadIdx.x; i < 3*3*16*32; i += 256) wlds[i] = W2[i];
    __syncthreads();

    const int b   = blockIdx.z;
    const int tid = threadIdx.x;
    const int fg  = tid >> 7;                  // 0/1 -> filters [fg*16, fg*16+16)
    const int rem = tid & 127;
    const int ph  = blockIdx.y * 8  + (rem >> 4);
    const int pw  = blockIdx.x * 16 + (rem & 15);
    const bool valid = (ph < 62) && (pw < 62);
    const int hp = valid ? ph : 61;
    const int wp = valid ? pw : 61;

    const float* xb = p1 + (size_t)b * (127*127*16);
    const int h0 = 2*hp, w0 = 2*wp;

    float acc[4][16];
    #pragma unroll
    for (int f = 0; f < 16; ++f) {
        float bv = b2[fg*16 + f];
        acc[0][f]=bv; acc[1][f]=bv; acc[2][f]=bv; acc[3][f]=bv;
    }

    for (int kh = 0; kh < 3; ++kh)
    for (int kw = 0; kw < 3; ++kw) {
        #pragma unroll
        for (int c4 = 0; c4 < 4; ++c4) {
            float xr[4][4];
            #pragma unroll
            for (int p = 0; p < 4; ++p) {
                const int hh = h0 + (p >> 1) + kh;
                const int ww = w0 + (p & 1) + kw;
                const float4 xv = *(const float4*)(xb + ((size_t)hh*127 + ww)*16 + c4*4);
                xr[p][0]=xv.x; xr[p][1]=xv.y; xr[p][2]=xv.z; xr[p][3]=xv.w;
            }
            #pragma unroll
            for (int cc = 0; cc < 4; ++cc) {
                const float* wb_ = &wlds[((kh*3 + kw)*16 + c4*4 + cc) * 32 + fg*16];
                float wv[16];
                #pragma unroll
                for (int q = 0; q < 4; ++q) {
                    const float4 w4 = *(const float4*)(wb_ + 4*q);
                    wv[4*q+0]=w4.x; wv[4*q+1]=w4.y; wv[4*q+2]=w4.z; wv[4*q+3]=w4.w;
                }
                #pragma unroll
                for (int p = 0; p < 4; ++p) {
                    const float xc = xr[p][cc];
                    #pragma unroll
                    for (int f = 0; f < 16; ++f) acc[p][f] += xc * wv[f];
                }
            }
        }
    }

    if (valid) {
        float out[16];
        #pragma unroll
        for (int f = 0; f < 16; ++f) {
            float m = fmaxf(fmaxf(acc[0][f], acc[1][f]), fmaxf(acc[2][f], acc[3][f]));
            out[f] = fmaxf(m, 0.0f);
        }
        float* dst = p2 + (((size_t)b*62 + ph)*62 + pw) * 32 + fg*16;
        #pragma unroll
        for (int q = 0; q < 4; ++q)
            *(float4*)(dst + 4*q) = make_float4(out[4*q], out[4*q+1], out[4*q+2], out[4*q+3]);
    }
}

// ---------------------------------------------------------------- conv3+pool
// p2:(16,62,62,32)  W3:(3,3,32,32)  b3:(32) -> p3:(16,30,30,32)
__global__ __launch_bounds__(256) void conv3_pool_kernel(
    const float* __restrict__ p2, const float* __restrict__ W3,
    const float* __restrict__ b3, float* __restrict__ p3)
{
    __shared__ float wlds[3*3*32*32];          // 36 KB
    for (int i = threadIdx.x; i < 3*3*32*32; i += 256) wlds[i] = W3[i];
    __syncthreads();

    const int b   = blockIdx.z;
    const int tid = threadIdx.x;
    const int fg  = tid >> 7;
    const int rem = tid & 127;
    const int ph  = blockIdx.y * 8  + (rem >> 4);
    const int pw  = blockIdx.x * 16 + (rem & 15);
    const bool valid = (ph < 30) && (pw < 30);
    const int hp = valid ? ph : 29;
    const int wp = valid ? pw : 29;

    const float* xb = p2 + (size_t)b * (62*62*32);
    const int h0 = 2*hp, w0 = 2*wp;

    float acc[4][16];
    #pragma unroll
    for (int f = 0; f < 16; ++f) {
        float bv = b3[fg*16 + f];
        acc[0][f]=bv; acc[1][f]=bv; acc[2][f]=bv; acc[3][f]=bv;
    }

    for (int kh = 0; kh < 3; ++kh)
    for (int kw = 0; kw < 3; ++kw) {
        #pragma unroll
        for (int c4 = 0; c4 < 8; ++c4) {
            float xr[4][4];
            #pragma unroll
            for (int p = 0; p < 4; ++p) {
                const int hh = h0 + (p >> 1) + kh;
                const int ww = w0 + (p & 1) + kw;
                const float4 xv = *(const float4*)(xb + ((size_t)hh*62 + ww)*32 + c4*4);
                xr[p][0]=xv.x; xr[p][1]=xv.y; xr[p][2]=xv.z; xr[p][3]=xv.w;
            }
            #pragma unroll
            for (int cc = 0; cc < 4; ++cc) {
                const float* wb_ = &wlds[((kh*3 + kw)*32 + c4*4 + cc) * 32 + fg*16];
                float wv[16];
                #pragma unroll
                for (int q = 0; q < 4; ++q) {
                    const float4 w4 = *(const float4*)(wb_ + 4*q);
                    wv[4*q+0]=w4.x; wv[4*q+1]=w4.y; wv[4*q+2]=w4.z; wv[4*q+3]=w4.w;
                }
                #pragma unroll
                for (int p = 0; p < 4; ++p) {
                    const float xc = xr[p][cc];
                    #pragma unroll
                    for (int f = 0; f < 16; ++f) acc[p][f] += xc * wv[f];
                }
            }
        }
    }

    if (valid) {
        float out[16];
        #pragma unroll
        for (int f = 0; f < 16; ++f) {
            float m = fmaxf(fmaxf(acc[0][f], acc[1][f]), fmaxf(acc[2][f], acc[3][f]));
            out[f] = fmaxf(m, 0.0f);
        }
        float* dst = p3 + (((size_t)b*30 + ph)*30 + pw) * 32 + fg*16;
        #pragma unroll
        for (int q = 0; q < 4; ++q)
            *(float4*)(dst + 4*q) = make_float4(out[4*q], out[4*q+1], out[4*q+2], out[4*q+3]);
    }
}

// ----------------------------------------------------------------- head
__global__ __launch_bounds__(256) void head_kernel(
    const float* __restrict__ p3,
    const float* __restrict__ D1, const float* __restrict__ db1,
    const float* __restrict__ D2, const float* __restrict__ db2,
    const float* __restrict__ D3, const float* __restrict__ db3,
    float* __restrict__ theta)
{
    __shared__ float red[8][32];
    __shared__ float hmean[32];
    __shared__ float h1[64];
    __shared__ float h2[32];

    const int b   = blockIdx.x;
    const int tid = threadIdx.x;
    const int c = tid & 31, r = tid >> 5;       // r in 0..7

    const float* p = p3 + (size_t)b * (900*32);
    float s = 0.0f;
    for (int i = r; i < 900; i += 8) s += p[i*32 + c];
    red[r][c] = s;
    __syncthreads();

    if (tid < 32) {
        float m = 0.0f;
        #pragma unroll
        for (int j = 0; j < 8; ++j) m += red[j][tid];
        hmean[tid] = m * (1.0f / 900.0f);
    }
    __syncthreads();

    if (tid < 64) {
        float a = db1[tid];
        #pragma unroll
        for (int k = 0; k < 32; ++k) a += hmean[k] * D1[k*64 + tid];
        h1[tid] = fmaxf(a, 0.0f);
    }
    __syncthreads();

    if (tid < 32) {
        float a = db2[tid];
        #pragma unroll
        for (int k = 0; k < 64; ++k) a += h1[k] * D2[k*32 + tid];
        h2[tid] = fmaxf(a, 0.0f);
    }
    __syncthreads();

    if (tid < 6) {
        float a = db3[tid];
        #pragma unroll
        for (int k = 0; k < 32; ++k) a += h2[k] * D3[k*6 + tid];
        theta[b*6 + tid] = a;
    }
}

// ----------------------------------------------------------------- sampler
__global__ __launch_bounds__(256) void sampler_kernel(
    const float* __restrict__ x, const float* __restrict__ theta,
    float* __restrict__ out)
{
    const int t  = blockIdx.x * 256 + threadIdx.x;
    const int c4 = t & 7;
    const int w  = (t >> 3) & 255;
    const int h  = (t >> 11) & 255;
    const int b  = t >> 19;

    const float* th = theta + b*6;
    const float gx = -1.0f + (float)w * (2.0f / 255.0f);
    const float gy = -1.0f + (float)h * (2.0f / 255.0f);
    const float xS = th[0]*gx + th[1]*gy + th[2];
    const float yS = th[3]*gx + th[4]*gy + th[5];
    const float xp = 0.5f * (xS + 1.0f) * 254.0f;
    const float yp = 0.5f * (yS + 1.0f) * 254.0f;

    int x0 = (int)floorf(xp), y0 = (int)floorf(yp);
    int x1 = x0 + 1,          y1 = y0 + 1;
    x0 = x0 < 0 ? 0 : (x0 > 255 ? 255 : x0);
    x1 = x1 < 0 ? 0 : (x1 > 255 ? 255 : x1);
    y0 = y0 < 0 ? 0 : (y0 > 255 ? 255 : y0);
    y1 = y1 < 0 ? 0 : (y1 > 255 ? 255 : y1);

    const float x0f = (float)x0, x1f = (float)x1;
    const float y0f = (float)y0, y1f = (float)y1;
    const float wa = (x1f - xp) * (y1f - yp);
    const float wb = (x1f - xp) * (yp - y0f);
    const float wc = (xp - x0f) * (y1f - yp);
    const float wd = (xp - x0f) * (yp - y0f);

    const float* xb = x + (size_t)b * (256*256*32) + c4*4;
    const float4 Ia = *(const float4*)(xb + ((size_t)y0*256 + x0)*32);
    const float4 Ib = *(const float4*)(xb + ((size_t)y1*256 + x0)*32);
    const float4 Ic = *(const float4*)(xb + ((size_t)y0*256 + x1)*32);
    const float4 Id = *(const float4*)(xb + ((size_t)y1*256 + x1)*32);

    float4 o;
    o.x = wa*Ia.x + wb*Ib.x + wc*Ic.x + wd*Id.x;
    o.y = wa*Ia.y + wb*Ib.y + wc*Ic.y + wd*Id.y;
    o.z = wa*Ia.z + wb*Ib.z + wc*Ic.z + wd*Id.z;
    o.w = wa*Ia.w + wb*Ib.w + wc*Ic.w + wd*Id.w;
    ((float4*)out)[t] = o;
}

// ----------------------------------------------------------------- launch
extern "C" void kernel_launch(void* const* d_in, const int* in_sizes, int n_in,
                              void* d_out, int out_size, void* d_ws, size_t ws_size,
                              hipStream_t stream) {
    const float* x   = (const float*)d_in[0];
    const float* W1  = (const float*)d_in[1];
    const float* b1  = (const float*)d_in[2];
    const float* W2  = (const float*)d_in[3];
    const float* b2  = (const float*)d_in[4];
    const float* W3  = (const float*)d_in[5];
    const float* b3  = (const float*)d_in[6];
    const float* D1  = (const float*)d_in[7];
    const float* db1 = (const float*)d_in[8];
    const float* D2  = (const float*)d_in[9];
    const float* db2 = (const float*)d_in[10];
    const float* D3  = (const float*)d_in[11];
    const float* db3 = (const float*)d_in[12];
    float* out = (float*)d_out;

    float* p1    = (float*)d_ws;
    float* p2    = p1 + P1_ELEMS;
    float* p3    = p2 + P2_ELEMS;
    float* theta = p3 + P3_ELEMS;

    conv1_pool_kernel<<<dim3(8, 32, 16), 256, 0, stream>>>(x,  W1, b1, p1);
    conv2_pool_kernel<<<dim3(4, 8, 16),  256, 0, stream>>>(p1, W2, b2, p2);
    conv3_pool_kernel<<<dim3(2, 4, 16),  256, 0, stream>>>(p2, W3, b3, p3);
    head_kernel      <<<dim3(16),        256, 0, stream>>>(p3, D1, db1, D2, db2, D3, db3, theta);
    sampler_kernel   <<<dim3(32768),     256, 0, stream>>>(x, theta, out);
}

// Round 3
// 487.244 us; speedup vs baseline: 2.1255x; 1.0731x over previous
//
#include <hip/hip_runtime.h>
#include <hip/hip_bf16.h>

// Problem: STN  B=16, H=W=256, C=32, FILTER=64 (f4=16, f2=32)
//
// Workspace layout (floats):
//   p1    : 16*127*127*16 = 4,129,024
//   p2    : 16* 62* 62*32 = 1,968,128
//   p3    : 16* 30* 30*32 =   460,800
//   theta : 16*6          =        96

#define P1_ELEMS 4129024
#define P2_ELEMS 1968128
#define P3_ELEMS 460800

// ---------------------------------------------------------------- conv1+pool
// x:(16,256,256,32)  W1:(3,3,32,16)  b1:(16)  -> p1:(16,127,127,16)
// 256 thr = 4 waves; wave = one filter quad (uniform -> weights via s_load).
// Lane = pooled pixel (4 rows x 16 cols). Input tile 10x34 px in LDS,
// pixel stride 36 dwords (32 + 4 pad, 16B-aligned imm offsets).
#define C1_PXSTR 36
#define C1_ROWSTR (34*36)

__global__ __launch_bounds__(256) void conv1_pool_kernel(
    const float* __restrict__ x, const float* __restrict__ W1,
    const float* __restrict__ b1, float* __restrict__ p1)
{
    __shared__ float xt[10 * C1_ROWSTR];   // 48960 B

    const int tid = threadIdx.x;
    const int b   = blockIdx.z;
    const int ph0 = blockIdx.y * 4;
    const int pw0 = blockIdx.x * 16;
    const float* xb = x + (size_t)b * (256*256*32);

    for (int i = tid; i < 10*34*8; i += 256) {
        const int dr  = i / 272;
        const int rem = i - dr * 272;
        const int j   = rem >> 3;
        const int ch  = rem & 7;
        int r_in = 2*ph0 + dr; if (r_in > 255) r_in = 255;
        int c_in = 2*pw0 + j;  if (c_in > 255) c_in = 255;
        const float4 v = *(const float4*)(xb + ((size_t)r_in*256 + c_in)*32 + ch*4);
        *(float4*)(&xt[dr*C1_ROWSTR + j*C1_PXSTR + ch*4]) = v;
    }
    __syncthreads();

    const int fq   = __builtin_amdgcn_readfirstlane(tid >> 6);
    const int lane = tid & 63;
    const int row  = lane >> 4;
    const int col  = lane & 15;

    float4 a0, a1, a2, a3;
    {
        const float4 bv = *(const float4*)(b1 + 4*fq);
        a0 = bv; a1 = bv; a2 = bv; a3 = bv;
    }

    const float* xbase = &xt[(2*row)*C1_ROWSTR + (2*col)*C1_PXSTR];
    const float* wbase = W1 + 4*fq;

#define C1_FMA(A, XV) \
    A.x += XV.x*w0.x; A.y += XV.x*w0.y; A.z += XV.x*w0.z; A.w += XV.x*w0.w; \
    A.x += XV.y*w1.x; A.y += XV.y*w1.y; A.z += XV.y*w1.z; A.w += XV.y*w1.w; \
    A.x += XV.z*w2.x; A.y += XV.z*w2.y; A.z += XV.z*w2.z; A.w += XV.z*w2.w; \
    A.x += XV.w*w3.x; A.y += XV.w*w3.y; A.z += XV.w*w3.z; A.w += XV.w*w3.w;

    #pragma unroll 1
    for (int kh = 0; kh < 3; ++kh) {
      #pragma unroll 1
      for (int kw = 0; kw < 3; ++kw) {
        const float* xp_ = xbase + kh*C1_ROWSTR + kw*C1_PXSTR;
        const float* wp_ = wbase + (kh*3 + kw)*32*16;
        #pragma unroll
        for (int c4 = 0; c4 < 8; ++c4) {
            const float4 x0 = *(const float4*)(xp_ + 4*c4);
            const float4 x1 = *(const float4*)(xp_ + C1_PXSTR + 4*c4);
            const float4 x2 = *(const float4*)(xp_ + C1_ROWSTR + 4*c4);
            const float4 x3 = *(const float4*)(xp_ + C1_ROWSTR + C1_PXSTR + 4*c4);
            const float4 w0 = *(const float4*)(wp_ + (4*c4+0)*16);
            const float4 w1 = *(const float4*)(wp_ + (4*c4+1)*16);
            const float4 w2 = *(const float4*)(wp_ + (4*c4+2)*16);
            const float4 w3 = *(const float4*)(wp_ + (4*c4+3)*16);
            C1_FMA(a0, x0)
            C1_FMA(a1, x1)
            C1_FMA(a2, x2)
            C1_FMA(a3, x3)
        }
      }
    }

    const int ph = ph0 + row, pw = pw0 + col;
    if (ph < 127 && pw < 127) {
        float4 o;
        o.x = fmaxf(fmaxf(fmaxf(a0.x, a1.x), fmaxf(a2.x, a3.x)), 0.0f);
        o.y = fmaxf(fmaxf(fmaxf(a0.y, a1.y), fmaxf(a2.y, a3.y)), 0.0f);
        o.z = fmaxf(fmaxf(fmaxf(a0.z, a1.z), fmaxf(a2.z, a3.z)), 0.0f);
        o.w = fmaxf(fmaxf(fmaxf(a0.w, a1.w), fmaxf(a2.w, a3.w)), 0.0f);
        *(float4*)(p1 + (((size_t)b*127 + ph)*127 + pw) * 16 + 4*fq) = o;
    }
}

// ---------------------------------------------------------------- conv2+pool
// p1:(16,127,127,16)  W2:(3,3,16,32)  b2:(32) -> p2:(16,62,62,32)
// Wave = 8 filters (f0 = 8*wave). Tile 4x16 pooled, input 10x34 px x 16 ch,
// pixel stride 20 dwords. LDS 27200 B.
#define C2_PXSTR 20
#define C2_ROWSTR (34*20)

__global__ __launch_bounds__(256) void conv2_pool_kernel(
    const float* __restrict__ p1, const float* __restrict__ W2,
    const float* __restrict__ b2, float* __restrict__ p2)
{
    __shared__ float xt[10 * C2_ROWSTR];   // 27200 B

    const int tid = threadIdx.x;
    const int b   = blockIdx.z;
    const int ph0 = blockIdx.y * 4;
    const int pw0 = blockIdx.x * 16;
    const float* xb = p1 + (size_t)b * (127*127*16);

    for (int i = tid; i < 10*34*4; i += 256) {
        const int dr  = i / 136;
        const int rem = i - dr * 136;
        const int j   = rem >> 2;
        const int ch  = rem & 3;
        int r_in = 2*ph0 + dr; if (r_in > 126) r_in = 126;
        int c_in = 2*pw0 + j;  if (c_in > 126) c_in = 126;
        const float4 v = *(const float4*)(xb + ((size_t)r_in*127 + c_in)*16 + ch*4);
        *(float4*)(&xt[dr*C2_ROWSTR + j*C2_PXSTR + ch*4]) = v;
    }
    __syncthreads();

    const int wv   = __builtin_amdgcn_readfirstlane(tid >> 6);
    const int lane = tid & 63;
    const int row  = lane >> 4;
    const int col  = lane & 15;
    const int f0   = 8 * wv;

    float4 aA0, aA1, aA2, aA3;   // filters f0..f0+3
    float4 aB0, aB1, aB2, aB3;   // filters f0+4..f0+7
    {
        const float4 bvA = *(const float4*)(b2 + f0);
        const float4 bvB = *(const float4*)(b2 + f0 + 4);
        aA0 = bvA; aA1 = bvA; aA2 = bvA; aA3 = bvA;
        aB0 = bvB; aB1 = bvB; aB2 = bvB; aB3 = bvB;
    }

    const float* xbase = &xt[(2*row)*C2_ROWSTR + (2*col)*C2_PXSTR];
    const float* wbase = W2 + f0;

#define C2_FMA(AA, AB, XC, WA, WB) \
    AA.x += XC*WA.x; AA.y += XC*WA.y; AA.z += XC*WA.z; AA.w += XC*WA.w; \
    AB.x += XC*WB.x; AB.y += XC*WB.y; AB.z += XC*WB.z; AB.w += XC*WB.w;

    #pragma unroll 1
    for (int kh = 0; kh < 3; ++kh) {
      #pragma unroll 1
      for (int kw = 0; kw < 3; ++kw) {
        const float* xp_ = xbase + kh*C2_ROWSTR + kw*C2_PXSTR;
        const float* wp_ = wbase + (kh*3 + kw)*16*32;
        #pragma unroll
        for (int c4 = 0; c4 < 4; ++c4) {
            const float4 x0 = *(const float4*)(xp_ + 4*c4);
            const float4 x1 = *(const float4*)(xp_ + C2_PXSTR + 4*c4);
            const float4 x2 = *(const float4*)(xp_ + C2_ROWSTR + 4*c4);
            const float4 x3 = *(const float4*)(xp_ + C2_ROWSTR + C2_PXSTR + 4*c4);
            #pragma unroll
            for (int c = 0; c < 4; ++c) {
                const float4 wA = *(const float4*)(wp_ + (4*c4+c)*32);
                const float4 wB = *(const float4*)(wp_ + (4*c4+c)*32 + 4);
                const float xc0 = (c==0)?x0.x:(c==1)?x0.y:(c==2)?x0.z:x0.w;
                const float xc1 = (c==0)?x1.x:(c==1)?x1.y:(c==2)?x1.z:x1.w;
                const float xc2 = (c==0)?x2.x:(c==1)?x2.y:(c==2)?x2.z:x2.w;
                const float xc3 = (c==0)?x3.x:(c==1)?x3.y:(c==2)?x3.z:x3.w;
                C2_FMA(aA0, aB0, xc0, wA, wB)
                C2_FMA(aA1, aB1, xc1, wA, wB)
                C2_FMA(aA2, aB2, xc2, wA, wB)
                C2_FMA(aA3, aB3, xc3, wA, wB)
            }
        }
      }
    }

    const int ph = ph0 + row, pw = pw0 + col;
    if (ph < 62 && pw < 62) {
        float4 oA, oB;
        oA.x = fmaxf(fmaxf(fmaxf(aA0.x, aA1.x), fmaxf(aA2.x, aA3.x)), 0.0f);
        oA.y = fmaxf(fmaxf(fmaxf(aA0.y, aA1.y), fmaxf(aA2.y, aA3.y)), 0.0f);
        oA.z = fmaxf(fmaxf(fmaxf(aA0.z, aA1.z), fmaxf(aA2.z, aA3.z)), 0.0f);
        oA.w = fmaxf(fmaxf(fmaxf(aA0.w, aA1.w), fmaxf(aA2.w, aA3.w)), 0.0f);
        oB.x = fmaxf(fmaxf(fmaxf(aB0.x, aB1.x), fmaxf(aB2.x, aB3.x)), 0.0f);
        oB.y = fmaxf(fmaxf(fmaxf(aB0.y, aB1.y), fmaxf(aB2.y, aB3.y)), 0.0f);
        oB.z = fmaxf(fmaxf(fmaxf(aB0.z, aB1.z), fmaxf(aB2.z, aB3.z)), 0.0f);
        oB.w = fmaxf(fmaxf(fmaxf(aB0.w, aB1.w), fmaxf(aB2.w, aB3.w)), 0.0f);
        float* dst = p2 + (((size_t)b*62 + ph)*62 + pw) * 32 + f0;
        *(float4*)(dst)     = oA;
        *(float4*)(dst + 4) = oB;
    }
}

// ---------------------------------------------------------------- conv3+pool
// p2:(16,62,62,32)  W3:(3,3,32,32)  b3:(32) -> p3:(16,30,30,32)
// Same as conv1 layout (32 ch, stride 36) but 8 filters/wave like conv2.
__global__ __launch_bounds__(256) void conv3_pool_kernel(
    const float* __restrict__ p2, const float* __restrict__ W3,
    const float* __restrict__ b3, float* __restrict__ p3)
{
    __shared__ float xt[10 * C1_ROWSTR];   // 48960 B

    const int tid = threadIdx.x;
    const int b   = blockIdx.z;
    const int ph0 = blockIdx.y * 4;
    const int pw0 = blockIdx.x * 16;
    const float* xb = p2 + (size_t)b * (62*62*32);

    for (int i = tid; i < 10*34*8; i += 256) {
        const int dr  = i / 272;
        const int rem = i - dr * 272;
        const int j   = rem >> 3;
        const int ch  = rem & 7;
        int r_in = 2*ph0 + dr; if (r_in > 61) r_in = 61;
        int c_in = 2*pw0 + j;  if (c_in > 61) c_in = 61;
        const float4 v = *(const float4*)(xb + ((size_t)r_in*62 + c_in)*32 + ch*4);
        *(float4*)(&xt[dr*C1_ROWSTR + j*C1_PXSTR + ch*4]) = v;
    }
    __syncthreads();

    const int wv   = __builtin_amdgcn_readfirstlane(tid >> 6);
    const int lane = tid & 63;
    const int row  = lane >> 4;
    const int col  = lane & 15;
    const int f0   = 8 * wv;

    float4 aA0, aA1, aA2, aA3;
    float4 aB0, aB1, aB2, aB3;
    {
        const float4 bvA = *(const float4*)(b3 + f0);
        const float4 bvB = *(const float4*)(b3 + f0 + 4);
        aA0 = bvA; aA1 = bvA; aA2 = bvA; aA3 = bvA;
        aB0 = bvB; aB1 = bvB; aB2 = bvB; aB3 = bvB;
    }

    const float* xbase = &xt[(2*row)*C1_ROWSTR + (2*col)*C1_PXSTR];
    const float* wbase = W3 + f0;

    #pragma unroll 1
    for (int kh = 0; kh < 3; ++kh) {
      #pragma unroll 1
      for (int kw = 0; kw < 3; ++kw) {
        const float* xp_ = xbase + kh*C1_ROWSTR + kw*C1_PXSTR;
        const float* wp_ = wbase + (kh*3 + kw)*32*32;
        #pragma unroll
        for (int c4 = 0; c4 < 8; ++c4) {
            const float4 x0 = *(const float4*)(xp_ + 4*c4);
            const float4 x1 = *(const float4*)(xp_ + C1_PXSTR + 4*c4);
            const float4 x2 = *(const float4*)(xp_ + C1_ROWSTR + 4*c4);
            const float4 x3 = *(const float4*)(xp_ + C1_ROWSTR + C1_PXSTR + 4*c4);
            #pragma unroll
            for (int c = 0; c < 4; ++c) {
                const float4 wA = *(const float4*)(wp_ + (4*c4+c)*32);
                const float4 wB = *(const float4*)(wp_ + (4*c4+c)*32 + 4);
                const float xc0 = (c==0)?x0.x:(c==1)?x0.y:(c==2)?x0.z:x0.w;
                const float xc1 = (c==0)?x1.x:(c==1)?x1.y:(c==2)?x1.z:x1.w;
                const float xc2 = (c==0)?x2.x:(c==1)?x2.y:(c==2)?x2.z:x2.w;
                const float xc3 = (c==0)?x3.x:(c==1)?x3.y:(c==2)?x3.z:x3.w;
                C2_FMA(aA0, aB0, xc0, wA, wB)
                C2_FMA(aA1, aB1, xc1, wA, wB)
                C2_FMA(aA2, aB2, xc2, wA, wB)
                C2_FMA(aA3, aB3, xc3, wA, wB)
            }
        }
      }
    }

    const int ph = ph0 + row, pw = pw0 + col;
    if (ph < 30 && pw < 30) {
        float4 oA, oB;
        oA.x = fmaxf(fmaxf(fmaxf(aA0.x, aA1.x), fmaxf(aA2.x, aA3.x)), 0.0f);
        oA.y = fmaxf(fmaxf(fmaxf(aA0.y, aA1.y), fmaxf(aA2.y, aA3.y)), 0.0f);
        oA.z = fmaxf(fmaxf(fmaxf(aA0.z, aA1.z), fmaxf(aA2.z, aA3.z)), 0.0f);
        oA.w = fmaxf(fmaxf(fmaxf(aA0.w, aA1.w), fmaxf(aA2.w, aA3.w)), 0.0f);
        oB.x = fmaxf(fmaxf(fmaxf(aB0.x, aB1.x), fmaxf(aB2.x, aB3.x)), 0.0f);
        oB.y = fmaxf(fmaxf(fmaxf(aB0.y, aB1.y), fmaxf(aB2.y, aB3.y)), 0.0f);
        oB.z = fmaxf(fmaxf(fmaxf(aB0.z, aB1.z), fmaxf(aB2.z, aB3.z)), 0.0f);
        oB.w = fmaxf(fmaxf(fmaxf(aB0.w, aB1.w), fmaxf(aB2.w, aB3.w)), 0.0f);
        float* dst = p3 + (((size_t)b*30 + ph)*30 + pw) * 32 + f0;
        *(float4*)(dst)     = oA;
        *(float4*)(dst + 4) = oB;
    }
}

// ----------------------------------------------------------------- head
__global__ __launch_bounds__(256) void head_kernel(
    const float* __restrict__ p3,
    const float* __restrict__ D1, const float* __restrict__ db1,
    const float* __restrict__ D2, const float* __restrict__ db2,
    const float* __restrict__ D3, const float* __restrict__ db3,
    float* __restrict__ theta)
{
    __shared__ float red[8][32];
    __shared__ float hmean[32];
    __shared__ float h1[64];
    __shared__ float h2[32];

    const int b   = blockIdx.x;
    const int tid = threadIdx.x;
    const int c = tid & 31, r = tid >> 5;

    const float* p = p3 + (size_t)b * (900*32);
    float s = 0.0f;
    for (int i = r; i < 900; i += 8) s += p[i*32 + c];
    red[r][c] = s;
    __syncthreads();

    if (tid < 32) {
        float m = 0.0f;
        #pragma unroll
        for (int j = 0; j < 8; ++j) m += red[j][tid];
        hmean[tid] = m * (1.0f / 900.0f);
    }
    __syncthreads();

    if (tid < 64) {
        float a = db1[tid];
        #pragma unroll
        for (int k = 0; k < 32; ++k) a += hmean[k] * D1[k*64 + tid];
        h1[tid] = fmaxf(a, 0.0f);
    }
    __syncthreads();

    if (tid < 32) {
        float a = db2[tid];
        #pragma unroll
        for (int k = 0; k < 64; ++k) a += h1[k] * D2[k*32 + tid];
        h2[tid] = fmaxf(a, 0.0f);
    }
    __syncthreads();

    if (tid < 6) {
        float a = db3[tid];
        #pragma unroll
        for (int k = 0; k < 32; ++k) a += h2[k] * D3[k*6 + tid];
        theta[b*6 + tid] = a;
    }
}

// ----------------------------------------------------------------- sampler
__global__ __launch_bounds__(256) void sampler_kernel(
    const float* __restrict__ x, const float* __restrict__ theta,
    float* __restrict__ out)
{
    const int t  = blockIdx.x * 256 + threadIdx.x;
    const int c4 = t & 7;
    const int w  = (t >> 3) & 255;
    const int h  = (t >> 11) & 255;
    const int b  = t >> 19;

    const float* th = theta + b*6;
    const float gx = -1.0f + (float)w * (2.0f / 255.0f);
    const float gy = -1.0f + (float)h * (2.0f / 255.0f);
    const float xS = th[0]*gx + th[1]*gy + th[2];
    const float yS = th[3]*gx + th[4]*gy + th[5];
    const float xp = 0.5f * (xS + 1.0f) * 254.0f;
    const float yp = 0.5f * (yS + 1.0f) * 254.0f;

    int x0 = (int)floorf(xp), y0 = (int)floorf(yp);
    int x1 = x0 + 1,          y1 = y0 + 1;
    x0 = x0 < 0 ? 0 : (x0 > 255 ? 255 : x0);
    x1 = x1 < 0 ? 0 : (x1 > 255 ? 255 : x1);
    y0 = y0 < 0 ? 0 : (y0 > 255 ? 255 : y0);
    y1 = y1 < 0 ? 0 : (y1 > 255 ? 255 : y1);

    const float x0f = (float)x0, x1f = (float)x1;
    const float y0f = (float)y0, y1f = (float)y1;
    const float wa = (x1f - xp) * (y1f - yp);
    const float wb = (x1f - xp) * (yp - y0f);
    const float wc = (xp - x0f) * (y1f - yp);
    const float wd = (xp - x0f) * (yp - y0f);

    const float* xb = x + (size_t)b * (256*256*32) + c4*4;
    const float4 Ia = *(const float4*)(xb + ((size_t)y0*256 + x0)*32);
    const float4 Ib = *(const float4*)(xb + ((size_t)y1*256 + x0)*32);
    const float4 Ic = *(const float4*)(xb + ((size_t)y0*256 + x1)*32);
    const float4 Id = *(const float4*)(xb + ((size_t)y1*256 + x1)*32);

    float4 o;
    o.x = wa*Ia.x + wb*Ib.x + wc*Ic.x + wd*Id.x;
    o.y = wa*Ia.y + wb*Ib.y + wc*Ic.y + wd*Id.y;
    o.z = wa*Ia.z + wb*Ib.z + wc*Ic.z + wd*Id.z;
    o.w = wa*Ia.w + wb*Ib.w + wc*Ic.w + wd*Id.w;
    ((float4*)out)[t] = o;
}

// ----------------------------------------------------------------- launch
extern "C" void kernel_launch(void* const* d_in, const int* in_sizes, int n_in,
                              void* d_out, int out_size, void* d_ws, size_t ws_size,
                              hipStream_t stream) {
    const float* x   = (const float*)d_in[0];
    const float* W1  = (const float*)d_in[1];
    const float* b1  = (const float*)d_in[2];
    const float* W2  = (const float*)d_in[3];
    const float* b2  = (const float*)d_in[4];
    const float* W3  = (const float*)d_in[5];
    const float* b3  = (const float*)d_in[6];
    const float* D1  = (const float*)d_in[7];
    const float* db1 = (const float*)d_in[8];
    const float* D2  = (const float*)d_in[9];
    const float* db2 = (const float*)d_in[10];
    const float* D3  = (const float*)d_in[11];
    const float* db3 = (const float*)d_in[12];
    float* out = (float*)d_out;

    float* p1    = (float*)d_ws;
    float* p2    = p1 + P1_ELEMS;
    float* p3    = p2 + P2_ELEMS;
    float* theta = p3 + P3_ELEMS;

    conv1_pool_kernel<<<dim3(8, 32, 16), 256, 0, stream>>>(x,  W1, b1, p1);
    conv2_pool_kernel<<<dim3(4, 16, 16), 256, 0, stream>>>(p1, W2, b2, p2);
    conv3_pool_kernel<<<dim3(2, 8, 16),  256, 0, stream>>>(p2, W3, b3, p3);
    head_kernel      <<<dim3(16),        256, 0, stream>>>(p3, D1, db1, D2, db2, D3, db3, theta);
    sampler_kernel   <<<dim3(32768),     256, 0, stream>>>(x, theta, out);
}